// Round 9
// baseline (34968.008 us; speedup 1.0000x reference)
//
#include <hip/hip_runtime.h>
#include <hip/hip_bf16.h>
#include <stdint.h>

// Problem dims
#define Bn 128
#define Tn 512
#define En 512
#define Hn 2048
#define Vn 32000
#define R0 8           // h0 MALL ring depth
#define R1 4           // h1 MALL ring depth
#define HSLOT (Bn*Hn)

// flag word indices (ALL flags are MALL relaxed-agent atomics — r2-r7 proven)
#define NREP 8
#define FRELA 8192     // + i*16, i in [0,64): relay i copied h0 through step v
#define FRELB 9216     // + i*16
#define FLXP  10240    // + g*16: x-partial ready through step v (v = t+1 means slot for t ready)
#define FLC0  11264    // + g*16: role0 finished step v-1
#define FLC2  12288    // + g*16: role2 finished step v-1
#define FLC3  13312    // + g*16: role3 finished step v-1
#define XCNT  14336    // + xcd
#define FLAG_WORDS 16384
#define BAILLIM 16384  // fast watchdog: bail -> wrong answer, never a 600s timeout

typedef float f32x4 __attribute__((ext_vector_type(4)));
typedef short bf16x8 __attribute__((ext_vector_type(8)));
typedef unsigned long long u64;

__device__ __forceinline__ unsigned short f2b(float f) {
  uint32_t x = __builtin_bit_cast(uint32_t, f);
  uint32_t r = x + 0x7FFFu + ((x >> 16) & 1u);
  return (unsigned short)(r >> 16);
}

__device__ __forceinline__ uint32_t ldf(const uint32_t* p) {
  return __hip_atomic_load(p, __ATOMIC_RELAXED, __HIP_MEMORY_SCOPE_AGENT);
}
__device__ __forceinline__ void stf(uint32_t* p, uint32_t v) {
  __hip_atomic_store(p, v, __ATOMIC_RELAXED, __HIP_MEMORY_SCOPE_AGENT);
}
union U16x8 { bf16x8 v; u64 q[2]; uint4 u; };
__device__ __forceinline__ void drain_then_sync() {
  asm volatile("s_waitcnt vmcnt(0)" ::: "memory");
  __syncthreads();
}

// sc0 (L1-bypass, L2-served) batched loads for same-XCD data
#define LD16_L2(PA, PB) \
  asm volatile( \
      "global_load_dwordx4 %[t0], %[a], off sc0\n\t" \
      "global_load_dwordx4 %[t1], %[a], off offset:64 sc0\n\t" \
      "global_load_dwordx4 %[t2], %[a], off offset:128 sc0\n\t" \
      "global_load_dwordx4 %[t3], %[a], off offset:192 sc0\n\t" \
      "global_load_dwordx4 %[t4], %[a], off offset:256 sc0\n\t" \
      "global_load_dwordx4 %[t5], %[a], off offset:320 sc0\n\t" \
      "global_load_dwordx4 %[t6], %[a], off offset:384 sc0\n\t" \
      "global_load_dwordx4 %[t7], %[a], off offset:448 sc0\n\t" \
      "global_load_dwordx4 %[t8], %[b], off sc0\n\t" \
      "global_load_dwordx4 %[t9], %[b], off offset:64 sc0\n\t" \
      "global_load_dwordx4 %[ta], %[b], off offset:128 sc0\n\t" \
      "global_load_dwordx4 %[tb], %[b], off offset:192 sc0\n\t" \
      "global_load_dwordx4 %[tc], %[b], off offset:256 sc0\n\t" \
      "global_load_dwordx4 %[td], %[b], off offset:320 sc0\n\t" \
      "global_load_dwordx4 %[te], %[b], off offset:384 sc0\n\t" \
      "global_load_dwordx4 %[tf], %[b], off offset:448 sc0\n\t" \
      "s_waitcnt vmcnt(0)" \
      : [t0]"=&v"(v0), [t1]"=&v"(v1), [t2]"=&v"(v2), [t3]"=&v"(v3), \
        [t4]"=&v"(v4), [t5]"=&v"(v5), [t6]"=&v"(v6), [t7]"=&v"(v7), \
        [t8]"=&v"(v8), [t9]"=&v"(v9), [ta]"=&v"(va), [tb]"=&v"(vb), \
        [tc]"=&v"(vc), [td]"=&v"(vd), [te]"=&v"(ve), [tf]"=&v"(vf) \
      : [a]"v"(PA), [b]"v"(PB) : "memory"); \
  __builtin_amdgcn_sched_barrier(0)

__device__ __forceinline__ void ld_pb4(const float* b0, f32x4& o0, f32x4& o1, f32x4& o2, f32x4& o3) {
  asm volatile(
      "global_load_dwordx4 %0, %[a], off sc0\n\t"
      "global_load_dwordx4 %1, %[a], off offset:1024 sc0\n\t"
      "global_load_dwordx4 %2, %[a], off offset:2048 sc0\n\t"
      "global_load_dwordx4 %3, %[a], off offset:3072 sc0\n\t"
      "s_waitcnt vmcnt(0)"
      : "=&v"(o0), "=&v"(o1), "=&v"(o2), "=&v"(o3)
      : [a]"v"(b0) : "memory");
  __builtin_amdgcn_sched_barrier(0);
}

// ---------------- init / pack kernels (r7/r8-proven) ----------------

__global__ void zero3(uint32_t* a, int na, uint32_t* b, int nb, uint32_t* c, int nc) {
  int i = blockIdx.x * 256 + threadIdx.x;
  if (i < na) a[i] = 0u;
  if (i < nb) b[i] = 0u;
  if (i < nc) c[i] = 0u;
}

__global__ void pack_bias(const float* bih0, const float* bhh0,
                          const float* bih1, const float* bhh1,
                          float* bias0, float* bias1) {
  int i = blockIdx.x * 256 + threadIdx.x;
  bias0[i] = bih0[i] + bhh0[i];
  bias1[i] = bih1[i] + bhh1[i];
}

// 64 groups x 32 cols; packets (kt*2+ct)*64+l; lane l elem j:
// src[col=g*32+ct*16+(l&15)][k=kt*32+(l>>4)*8+j]
__global__ void pack_w32(const float* __restrict__ src, int Kd, uint4* __restrict__ img) {
  int tid = blockIdx.x * 256 + threadIdx.x;
  int per = Kd * 4;
  int g = tid / per, p = tid - g * per;
  int l = p & 63, q = p >> 6;
  int ct = q & 1, kt = q >> 1;
  int col = g * 32 + ct * 16 + (l & 15);
  int k0 = kt * 32 + (l >> 4) * 8;
  const float* s = src + (size_t)col * Kd + k0;
  unsigned short o[8];
#pragma unroll
  for (int j = 0; j < 8; ++j) o[j] = f2b(s[j]);
  img[tid] = *reinterpret_cast<uint4*>(o);
}

__global__ void pack_imgW1(const float* __restrict__ W1, uint4* __restrict__ img) {
  int tid = blockIdx.x * 256 + threadIdx.x;
  int grp = tid >> 12;
  int p = tid & 4095;
  int l = p & 63;
  int kt = p >> 6;
  int col = grp * 16 + (l & 15);
  int k0 = kt * 32 + (l >> 4) * 8;
  const float* src = W1 + (size_t)col * Hn + k0;
  unsigned short o[8];
#pragma unroll
  for (int j = 0; j < 8; ++j) o[j] = f2b(src[j]);
  img[tid] = *reinterpret_cast<uint4*>(o);
}

__global__ void pack_imgW2(const float* __restrict__ W2, uint4* __restrict__ img) {
  int tid = blockIdx.x * 256 + threadIdx.x;
  int grp = tid >> 12;
  int p = tid & 4095;
  int l = p & 63;
  int ckt = p >> 6;
  int ct = ckt & 3, kt = ckt >> 2;
  int col = grp * 64 + ct * 16 + (l & 15);
  int k0 = kt * 32 + (l >> 4) * 8;
  const float* src = W2 + (size_t)col * En + k0;
  unsigned short o[8];
#pragma unroll
  for (int j = 0; j < 8; ++j) o[j] = f2b(src[j]);
  img[tid] = *reinterpret_cast<uint4*>(o);
}

__global__ void gather_x(const int* __restrict__ ids, const float* __restrict__ emb,
                         uint4* __restrict__ xall) {
  int tid = blockIdx.x * 256 + threadIdx.x;
  int t = tid >> 13;
  int r = tid & 8191;
  int b = r >> 6;
  int e8 = r & 63;
  int id = ids[b * Tn + t];
  const float* src = emb + (size_t)id * En + e8 * 8;
  unsigned short o[8];
#pragma unroll
  for (int j = 0; j < 8; ++j) o[j] = f2b(src[j]);
  xall[tid] = *reinterpret_cast<uint4*>(o);
}

// ---------------- persistent RNN kernel v10 ----------------
// 256 blocks x 256 threads, 1/CU. Slot-grab by XCC_ID: slot in [0,32),
// role = slot>>3, gg = slot&7, g = xcd*8+gg (32 cols per group).
//  role0: h0 = tanh(Whh0.h0[t-1] (local xh0 copy) + xpbuf + b0) -> MALL h0ring, fA0
//  role1: relay h0[t],h1[t] batch-row slice MALL->local xh0/xh1; x-partial (t+1) -> xpbuf
//  role2: Wih1.h0[t] (local xh0) -> qpbuf, FLC2
//  role3: h1 = tanh(Whh1.h1[t-1] (local xh1) + qpbuf + b1) -> MALL h1ring, fB0
// ALL flags MALL (progress independent of XCD mapping -> no deadlock possible from
// mapping). Only bulk data uses locality; wrong mapping -> loud absmax failure.
// Step DAG: role0 -> relayA -> role2 -> role3 -> relayB -> relayC (acyclic; audited).

#define MFMA4(AF0, AF1, KT) do { \
    bf16x8 bw0 = wlds[((KT) * 2) * 64 + l]; \
    bf16x8 bw1 = wlds[((KT) * 2 + 1) * 64 + l]; \
    acc[0][0] = __builtin_amdgcn_mfma_f32_16x16x32_bf16(AF0, bw0, acc[0][0], 0, 0, 0); \
    acc[0][1] = __builtin_amdgcn_mfma_f32_16x16x32_bf16(AF0, bw1, acc[0][1], 0, 0, 0); \
    acc[1][0] = __builtin_amdgcn_mfma_f32_16x16x32_bf16(AF1, bw0, acc[1][0], 0, 0, 0); \
    acc[1][1] = __builtin_amdgcn_mfma_f32_16x16x32_bf16(AF1, bw1, acc[1][1], 0, 0, 0); \
  } while (0)

#define KLOOP_L2(HP, STRIDE, NB) do { \
    const unsigned short* pr0_ = (HP) + (size_t)row0 * (STRIDE) + kq * 8; \
    const unsigned short* pr1_ = pr0_ + (size_t)16 * (STRIDE); \
    for (int b_ = 0; b_ < (NB); ++b_) { \
      const unsigned short* pa_ = pr0_ + b_ * 256; \
      const unsigned short* pb_ = pr1_ + b_ * 256; \
      bf16x8 v0,v1,v2,v3,v4,v5,v6,v7,v8,v9,va,vb,vc,vd,ve,vf; \
      LD16_L2(pa_, pb_); \
      const int ktg_ = b_ * 8; \
      MFMA4(v0, v8, ktg_ + 0); MFMA4(v1, v9, ktg_ + 1); \
      MFMA4(v2, va, ktg_ + 2); MFMA4(v3, vb, ktg_ + 3); \
      MFMA4(v4, vc, ktg_ + 4); MFMA4(v5, vd, ktg_ + 5); \
      MFMA4(v6, ve, ktg_ + 6); MFMA4(v7, vf, ktg_ + 7); \
    } \
  } while (0)

__global__ __launch_bounds__(256, 1) void rnn_persist(
    const uint4* __restrict__ imgWhh0, const uint4* __restrict__ imgWih0,
    const uint4* __restrict__ imgWih1, const uint4* __restrict__ imgWhh1,
    const unsigned short* __restrict__ xall,
    unsigned short* __restrict__ h0ring, unsigned short* __restrict__ h1ring,
    unsigned short* __restrict__ xh0, unsigned short* __restrict__ xh1,
    float* __restrict__ xpbuf, float* __restrict__ qpbuf,
    const float* __restrict__ bias0, const float* __restrict__ bias1,
    uint32_t* flags) {
  __shared__ uint4 smem[8192];  // 128 KiB -> 1 block/CU
  __shared__ uint32_t rs[2];
  const int tid = threadIdx.x;
  const int w = tid >> 6, l = tid & 63, l15 = l & 15, kq = l >> 4;

  if (tid == 0) {
    uint32_t xcc;
    asm volatile("s_getreg_b32 %0, hwreg(HW_REG_XCC_ID)" : "=s"(xcc));
    xcc &= 7u;
    uint32_t slot = __hip_atomic_fetch_add(flags + XCNT + xcc, 1u,
                                           __ATOMIC_RELAXED, __HIP_MEMORY_SCOPE_AGENT);
    rs[0] = xcc; rs[1] = slot & 31u;
  }
  __syncthreads();
  const int xcd = (int)rs[0];
  const int slot = (int)rs[1];
  const int role = slot >> 3, gg = slot & 7;
  const int g = xcd * 8 + gg;
  const int myrep = blockIdx.x & (NREP - 1);
  const uint32_t* fA0r = flags + (size_t)myrep * 1024;        // + g
  const uint32_t* fB0r = flags + (size_t)myrep * 1024 + 128;  // + g

  unsigned short* myxh0 = xh0 + (size_t)xcd * 2 * HSLOT;
  unsigned short* myxh1 = xh1 + (size_t)xcd * 2 * HSLOT;
  float* myxp = xpbuf + (size_t)g * 2 * 4096;
  float* myqp = qpbuf + (size_t)g * 2 * 4096;

  {  // stage weights
    const uint4* wsrc; int npkt;
    if (role == 0)      { wsrc = imgWhh0 + (size_t)g * 8192; npkt = 8192; }
    else if (role == 1) { wsrc = imgWih0 + (size_t)g * 2048; npkt = 2048; }
    else if (role == 2) { wsrc = imgWih1 + (size_t)g * 8192; npkt = 8192; }
    else                { wsrc = imgWhh1 + (size_t)g * 8192; npkt = 8192; }
    for (int i = tid; i < npkt; i += 256) smem[i] = wsrc[i];
  }
  __syncthreads();
  const bf16x8* wlds = reinterpret_cast<const bf16x8*>(smem);
  const int row0 = w * 32 + l15;
  const int colbase = g * 32;

  if (role == 1) {
    // pre-loop: x-partial for t=0
    {
      f32x4 acc[2][2];
#pragma unroll
      for (int mt = 0; mt < 2; ++mt)
#pragma unroll
        for (int ct = 0; ct < 2; ++ct) acc[mt][ct] = (f32x4){0.f, 0.f, 0.f, 0.f};
#pragma unroll 2
      for (int kt = 0; kt < 16; ++kt) {
        bf16x8 a0 = *reinterpret_cast<const bf16x8*>(xall + kt * 32 + (size_t)row0 * En + kq * 8);
        bf16x8 a1 = *reinterpret_cast<const bf16x8*>(xall + kt * 32 + (size_t)(row0 + 16) * En + kq * 8);
        MFMA4(a0, a1, kt);
      }
#pragma unroll
      for (int mt = 0; mt < 2; ++mt)
#pragma unroll
        for (int ct = 0; ct < 2; ++ct)
          *reinterpret_cast<f32x4*>(myxp + (w * 4 + mt * 2 + ct) * 256 + l * 4) = acc[mt][ct];
      drain_then_sync();
      if (tid == 0) stf(flags + FLXP + (size_t)g * 16, 1u);
    }
    for (int t = 0; t < Tn; ++t) {
      // Phase A: copy h0[t] rows [gg*16, gg*16+16)
      {
        int guard = 0;
        for (;;) {
          int ok = 1;
          if (tid < 64) ok = ((int)ldf(fA0r + tid) >= t + 1);
          else if (tid >= 64 && tid < 72) ok = ((int)ldf(flags + FLC0 + (size_t)(xcd * 8 + tid - 64) * 16) >= t);
          else if (tid >= 72 && tid < 80) ok = ((int)ldf(flags + FLC2 + (size_t)(xcd * 8 + tid - 72) * 16) >= t - 1);
          if (++guard > BAILLIM) ok = 1;
          if (__syncthreads_and(ok)) break;
          __builtin_amdgcn_s_sleep(1);
        }
      }
      {
        const u64* src = (const u64*)(h0ring + (size_t)(t % R0) * HSLOT + (size_t)(gg * 16) * Hn);
        uint4* dst = (uint4*)(myxh0 + (size_t)(t & 1) * HSLOT + (size_t)(gg * 16) * Hn);
#pragma unroll 4
        for (int i = tid; i < 4096; i += 256) {
          U16x8 u;
          u.q[0] = __hip_atomic_load(src + (size_t)i * 2,     __ATOMIC_RELAXED, __HIP_MEMORY_SCOPE_AGENT);
          u.q[1] = __hip_atomic_load(src + (size_t)i * 2 + 1, __ATOMIC_RELAXED, __HIP_MEMORY_SCOPE_AGENT);
          dst[i] = u.u;
        }
      }
      drain_then_sync();
      if (tid == 0) stf(flags + FRELA + (size_t)g * 16, (uint32_t)(t + 1));
      // Phase B: copy h1[t] slice
      {
        int guard = 0;
        for (;;) {
          int ok = 1;
          if (tid < 64) ok = ((int)ldf(fB0r + tid) >= t + 1);
          else if (tid >= 64 && tid < 72) ok = ((int)ldf(flags + FLC3 + (size_t)(xcd * 8 + tid - 64) * 16) >= t);
          if (++guard > BAILLIM) ok = 1;
          if (__syncthreads_and(ok)) break;
          __builtin_amdgcn_s_sleep(1);
        }
      }
      {
        const u64* src = (const u64*)(h1ring + (size_t)(t % R1) * HSLOT + (size_t)(gg * 16) * Hn);
        uint4* dst = (uint4*)(myxh1 + (size_t)(t & 1) * HSLOT + (size_t)(gg * 16) * Hn);
#pragma unroll 4
        for (int i = tid; i < 4096; i += 256) {
          U16x8 u;
          u.q[0] = __hip_atomic_load(src + (size_t)i * 2,     __ATOMIC_RELAXED, __HIP_MEMORY_SCOPE_AGENT);
          u.q[1] = __hip_atomic_load(src + (size_t)i * 2 + 1, __ATOMIC_RELAXED, __HIP_MEMORY_SCOPE_AGENT);
          dst[i] = u.u;
        }
      }
      drain_then_sync();
      if (tid == 0) stf(flags + FRELB + (size_t)g * 16, (uint32_t)(t + 1));
      // Phase C: x-partial for t+1 (xpbuf slot (t+1)&1 free: FLC0>=t held by Phase A wait)
      if (t + 1 < Tn) {
        const unsigned short* xt = xall + (size_t)(t + 1) * (Bn * En);
        f32x4 acc[2][2];
#pragma unroll
        for (int mt = 0; mt < 2; ++mt)
#pragma unroll
          for (int ct = 0; ct < 2; ++ct) acc[mt][ct] = (f32x4){0.f, 0.f, 0.f, 0.f};
#pragma unroll 2
        for (int kt = 0; kt < 16; ++kt) {
          bf16x8 a0 = *reinterpret_cast<const bf16x8*>(xt + kt * 32 + (size_t)row0 * En + kq * 8);
          bf16x8 a1 = *reinterpret_cast<const bf16x8*>(xt + kt * 32 + (size_t)(row0 + 16) * En + kq * 8);
          MFMA4(a0, a1, kt);
        }
#pragma unroll
        for (int mt = 0; mt < 2; ++mt)
#pragma unroll
          for (int ct = 0; ct < 2; ++ct)
            *reinterpret_cast<f32x4*>(myxp + (size_t)((t + 1) & 1) * 4096 + (w * 4 + mt * 2 + ct) * 256 + l * 4) = acc[mt][ct];
        drain_then_sync();
        if (tid == 0) stf(flags + FLXP + (size_t)g * 16, (uint32_t)(t + 2));
      }
    }
  } else if (role == 0) {
    for (int t = 0; t < Tn; ++t) {
      {
        int guard = 0;
        for (;;) {
          int ok = 1;
          if (tid < 8) ok = ((int)ldf(flags + FRELA + (size_t)(xcd * 8 + tid) * 16) >= t);
          else if (tid == 8) ok = ((int)ldf(flags + FLXP + (size_t)g * 16) >= t + 1);
          else if (t >= R0 && tid >= 64 && tid < 128)
            ok = ((int)ldf(flags + FRELA + (size_t)(tid - 64) * 16) >= t - R0 + 1);
          if (++guard > BAILLIM) ok = 1;
          if (__syncthreads_and(ok)) break;
          __builtin_amdgcn_s_sleep(1);
        }
      }
      f32x4 acc[2][2];
#pragma unroll
      for (int mt = 0; mt < 2; ++mt)
#pragma unroll
        for (int ct = 0; ct < 2; ++ct) acc[mt][ct] = (f32x4){0.f, 0.f, 0.f, 0.f};
      if (t > 0) {
        const unsigned short* hp = myxh0 + (size_t)((t - 1) & 1) * HSLOT;
        KLOOP_L2(hp, Hn, 8);
      }
      {
        const float* pb2 = myxp + (size_t)(t & 1) * 4096 + (w * 4) * 256 + l * 4;
        f32x4 p0, p1, p2, p3;
        ld_pb4(pb2, p0, p1, p2, p3);
        acc[0][0] += p0; acc[0][1] += p1; acc[1][0] += p2; acc[1][1] += p3;
      }
      unsigned short* hdst = h0ring + (size_t)(t % R0) * HSLOT;
#pragma unroll
      for (int mt = 0; mt < 2; ++mt) {
#pragma unroll
        for (int ct = 0; ct < 2; ++ct) {
          const int col = colbase + ct * 16 + l15;
          const float bb = bias0[col];
#pragma unroll
          for (int r = 0; r < 4; ++r) {
            float v = tanhf(acc[mt][ct][r] + bb);
            int bo = f2b(v);
            int po = __shfl_down(bo, 1);
            if ((l15 & 1) == 0) {
              const int row = w * 32 + mt * 16 + kq * 4 + r;
              uint32_t packed = (uint32_t)(unsigned short)bo | ((uint32_t)(unsigned short)po << 16);
              stf((uint32_t*)(hdst + (size_t)row * Hn + col), packed);
            }
          }
        }
      }
      drain_then_sync();
      if (tid < NREP) stf(flags + (size_t)tid * 1024 + g, (uint32_t)(t + 1));
      else if (tid == 8) stf(flags + FLC0 + (size_t)g * 16, (uint32_t)(t + 1));
    }
  } else if (role == 2) {
    for (int t = 0; t < Tn; ++t) {
      {
        int guard = 0;
        for (;;) {
          int ok = 1;
          if (tid < 8) ok = ((int)ldf(flags + FRELA + (size_t)(xcd * 8 + tid) * 16) >= t + 1);
          else if (tid == 8) ok = ((int)ldf(flags + FLC3 + (size_t)g * 16) >= t - 1);
          if (++guard > BAILLIM) ok = 1;
          if (__syncthreads_and(ok)) break;
          __builtin_amdgcn_s_sleep(1);
        }
      }
      f32x4 acc[2][2];
#pragma unroll
      for (int mt = 0; mt < 2; ++mt)
#pragma unroll
        for (int ct = 0; ct < 2; ++ct) acc[mt][ct] = (f32x4){0.f, 0.f, 0.f, 0.f};
      {
        const unsigned short* hp = myxh0 + (size_t)(t & 1) * HSLOT;
        KLOOP_L2(hp, Hn, 8);
      }
#pragma unroll
      for (int mt = 0; mt < 2; ++mt)
#pragma unroll
        for (int ct = 0; ct < 2; ++ct)
          *reinterpret_cast<f32x4*>(myqp + (size_t)(t & 1) * 4096 + (w * 4 + mt * 2 + ct) * 256 + l * 4) = acc[mt][ct];
      drain_then_sync();
      if (tid == 0) stf(flags + FLC2 + (size_t)g * 16, (uint32_t)(t + 1));
    }
  } else {
    for (int t = 0; t < Tn; ++t) {
      {
        int guard = 0;
        for (;;) {
          int ok = 1;
          if (tid < 8) ok = ((int)ldf(flags + FRELB + (size_t)(xcd * 8 + tid) * 16) >= t);
          else if (tid == 8) ok = ((int)ldf(flags + FLC2 + (size_t)g * 16) >= t + 1);
          else if (t >= R1 && tid >= 64 && tid < 128)
            ok = ((int)ldf(flags + FRELB + (size_t)(tid - 64) * 16) >= t - R1 + 1);
          if (++guard > BAILLIM) ok = 1;
          if (__syncthreads_and(ok)) break;
          __builtin_amdgcn_s_sleep(1);
        }
      }
      f32x4 acc[2][2];
#pragma unroll
      for (int mt = 0; mt < 2; ++mt)
#pragma unroll
        for (int ct = 0; ct < 2; ++ct) acc[mt][ct] = (f32x4){0.f, 0.f, 0.f, 0.f};
      if (t > 0) {
        const unsigned short* hp = myxh1 + (size_t)((t - 1) & 1) * HSLOT;
        KLOOP_L2(hp, Hn, 8);
      }
      {
        const float* pb2 = myqp + (size_t)(t & 1) * 4096 + (w * 4) * 256 + l * 4;
        f32x4 p0, p1, p2, p3;
        ld_pb4(pb2, p0, p1, p2, p3);
        acc[0][0] += p0; acc[0][1] += p1; acc[1][0] += p2; acc[1][1] += p3;
      }
      unsigned short* hdst = h1ring + (size_t)(t % R1) * HSLOT;
#pragma unroll
      for (int mt = 0; mt < 2; ++mt) {
#pragma unroll
        for (int ct = 0; ct < 2; ++ct) {
          const int col = colbase + ct * 16 + l15;
          const float bb = bias1[col];
#pragma unroll
          for (int r = 0; r < 4; ++r) {
            float v = tanhf(acc[mt][ct][r] + bb);
            int bo = f2b(v);
            int po = __shfl_down(bo, 1);
            if ((l15 & 1) == 0) {
              const int row = w * 32 + mt * 16 + kq * 4 + r;
              uint32_t packed = (uint32_t)(unsigned short)bo | ((uint32_t)(unsigned short)po << 16);
              stf((uint32_t*)(hdst + (size_t)row * Hn + col), packed);
            }
          }
        }
      }
      drain_then_sync();
      if (tid < NREP) stf(flags + (size_t)tid * 1024 + 128 + g, (uint32_t)(t + 1));
      else if (tid == 8) stf(flags + FLC3 + (size_t)g * 16, (uint32_t)(t + 1));
    }
  }
}

// ---------------- head (proven) ----------------
__global__ __launch_bounds__(256) void head1(const uint4* __restrict__ imgW1,
                                             const unsigned short* __restrict__ h1f,
                                             const float* __restrict__ b1,
                                             unsigned short* __restrict__ a1) {
  __shared__ uint4 smem[4096];
  const int tid = threadIdx.x;
  const int w = tid >> 6, l = tid & 63, l15 = l & 15, kq = l >> 4;
  const int g = blockIdx.x;
  const uint4* src = imgW1 + (size_t)g * 4096;
  for (int i = tid; i < 4096; i += 256) smem[i] = src[i];
  __syncthreads();
  const bf16x8* wlds = reinterpret_cast<const bf16x8*>(smem);
  const int row0 = w * 32 + l15;
  f32x4 acc[2];
  acc[0] = (f32x4){0.f, 0.f, 0.f, 0.f};
  acc[1] = (f32x4){0.f, 0.f, 0.f, 0.f};
#pragma unroll 4
  for (int kt = 0; kt < 64; ++kt) {
    bf16x8 af0 = *reinterpret_cast<const bf16x8*>(h1f + (size_t)row0 * Hn + kt * 32 + kq * 8);
    bf16x8 af1 = *reinterpret_cast<const bf16x8*>(h1f + (size_t)(row0 + 16) * Hn + kt * 32 + kq * 8);
    bf16x8 bf = wlds[kt * 64 + l];
    acc[0] = __builtin_amdgcn_mfma_f32_16x16x32_bf16(af0, bf, acc[0], 0, 0, 0);
    acc[1] = __builtin_amdgcn_mfma_f32_16x16x32_bf16(af1, bf, acc[1], 0, 0, 0);
  }
  const int col = g * 16 + l15;
  const float bb = b1[col];
#pragma unroll
  for (int mt = 0; mt < 2; ++mt)
#pragma unroll
    for (int r = 0; r < 4; ++r) {
      float v = fmaxf(acc[mt][r] + bb, 0.f);
      const int row = w * 32 + mt * 16 + kq * 4 + r;
      a1[(size_t)row * En + col] = f2b(v);
    }
}

__global__ __launch_bounds__(256) void head2(const uint4* __restrict__ imgW2,
                                             const unsigned short* __restrict__ a1,
                                             const float* __restrict__ b2,
                                             float* __restrict__ out) {
  __shared__ uint4 smem[4096];
  const int tid = threadIdx.x;
  const int w = tid >> 6, l = tid & 63, l15 = l & 15, kq = l >> 4;
  const int g = blockIdx.x;
  const uint4* src = imgW2 + (size_t)g * 4096;
  for (int i = tid; i < 4096; i += 256) smem[i] = src[i];
  __syncthreads();
  const bf16x8* wlds = reinterpret_cast<const bf16x8*>(smem);
  const int row0 = w * 32 + l15;
  f32x4 acc[2][4];
#pragma unroll
  for (int mt = 0; mt < 2; ++mt)
#pragma unroll
    for (int ct = 0; ct < 4; ++ct) acc[mt][ct] = (f32x4){0.f, 0.f, 0.f, 0.f};
#pragma unroll
  for (int kt = 0; kt < 16; ++kt) {
    bf16x8 af0 = *reinterpret_cast<const bf16x8*>(a1 + (size_t)row0 * En + kt * 32 + kq * 8);
    bf16x8 af1 = *reinterpret_cast<const bf16x8*>(a1 + (size_t)(row0 + 16) * En + kt * 32 + kq * 8);
#pragma unroll
    for (int ct = 0; ct < 4; ++ct) {
      bf16x8 bf = wlds[(kt * 4 + ct) * 64 + l];
      acc[0][ct] = __builtin_amdgcn_mfma_f32_16x16x32_bf16(af0, bf, acc[0][ct], 0, 0, 0);
      acc[1][ct] = __builtin_amdgcn_mfma_f32_16x16x32_bf16(af1, bf, acc[1][ct], 0, 0, 0);
    }
  }
#pragma unroll
  for (int mt = 0; mt < 2; ++mt)
#pragma unroll
    for (int ct = 0; ct < 4; ++ct) {
      const int col = g * 64 + ct * 16 + l15;
      const float bb = b2[col];
#pragma unroll
      for (int r = 0; r < 4; ++r) {
        const int row = w * 32 + mt * 16 + kq * 4 + r;
        out[(size_t)row * Vn + col] = acc[mt][ct][r] + bb;
      }
    }
}

// ---------------- launch ----------------
extern "C" void kernel_launch(void* const* d_in, const int* in_sizes, int n_in,
                              void* d_out, int out_size, void* d_ws, size_t ws_size,
                              hipStream_t stream) {
  (void)in_sizes; (void)n_in; (void)out_size;
  const int* ids    = (const int*)d_in[0];
  const float* emb  = (const float*)d_in[1];
  const float* Wih0 = (const float*)d_in[2];
  const float* Whh0 = (const float*)d_in[3];
  const float* bih0 = (const float*)d_in[4];
  const float* bhh0 = (const float*)d_in[5];
  const float* Wih1 = (const float*)d_in[6];
  const float* Whh1 = (const float*)d_in[7];
  const float* bih1 = (const float*)d_in[8];
  const float* bhh1 = (const float*)d_in[9];
  const float* W1   = (const float*)d_in[10];
  const float* b1   = (const float*)d_in[11];
  const float* W2   = (const float*)d_in[12];
  const float* b2   = (const float*)d_in[13];
  float* out = (float*)d_out;

  char* ws = (char*)d_ws;
  size_t o = 0;
  auto alloc = [&](size_t bytes) -> char* {
    char* p = ws + o;
    o += (bytes + 255) & ~(size_t)255;
    return p;
  };
  uint32_t* flags = (uint32_t*)alloc(FLAG_WORDS * 4);
  float* bias0 = (float*)alloc(Hn * 4);
  float* bias1 = (float*)alloc(Hn * 4);
  unsigned short* h0ring = (unsigned short*)alloc((size_t)R0 * HSLOT * 2);
  unsigned short* h1ring = (unsigned short*)alloc((size_t)R1 * HSLOT * 2);
  unsigned short* xh0 = (unsigned short*)alloc(8ull * 2 * HSLOT * 2);
  unsigned short* xh1 = (unsigned short*)alloc(8ull * 2 * HSLOT * 2);
  float* xpbuf = (float*)alloc(64ull * 2 * 4096 * 4);
  float* qpbuf = (float*)alloc(64ull * 2 * 4096 * 4);
  unsigned short* a1 = (unsigned short*)alloc((size_t)Bn * En * 2);
  uint4* imgWhh0 = (uint4*)alloc(64ull * 8192 * 16);
  uint4* imgWih0 = (uint4*)alloc(64ull * 2048 * 16);
  uint4* imgWih1 = (uint4*)alloc(64ull * 8192 * 16);
  uint4* imgWhh1 = (uint4*)alloc(64ull * 8192 * 16);
  uint4* imgW1 = (uint4*)alloc(32ull * 4096 * 16);
  uint4* imgW2 = (uint4*)alloc(500ull * 4096 * 16);
  uint4* xall  = (uint4*)alloc((size_t)Tn * Bn * En * 2);
  if (o > ws_size) return;  // fail visibly, no OOB

  zero3<<<64, 256, 0, stream>>>(flags, FLAG_WORDS, flags, 0, flags, 0);
  pack_bias<<<8, 256, 0, stream>>>(bih0, bhh0, bih1, bhh1, bias0, bias1);
  pack_w32<<<2048, 256, 0, stream>>>(Whh0, 2048, imgWhh0);
  pack_w32<<<512, 256, 0, stream>>>(Wih0, 512, imgWih0);
  pack_w32<<<2048, 256, 0, stream>>>(Wih1, 2048, imgWih1);
  pack_w32<<<2048, 256, 0, stream>>>(Whh1, 2048, imgWhh1);
  pack_imgW1<<<512, 256, 0, stream>>>(W1, imgW1);
  pack_imgW2<<<8000, 256, 0, stream>>>(W2, imgW2);
  gather_x<<<16384, 256, 0, stream>>>(ids, emb, xall);

  rnn_persist<<<256, 256, 0, stream>>>(imgWhh0, imgWih0, imgWih1, imgWhh1,
                                       (const unsigned short*)xall, h0ring, h1ring,
                                       xh0, xh1, xpbuf, qpbuf, bias0, bias1, flags);

  head1<<<32, 256, 0, stream>>>(imgW1, h1ring + (size_t)(511 % R1) * HSLOT, b1, a1);
  head2<<<500, 256, 0, stream>>>(imgW2, a1, b2, out);
}